// Round 1
// 465.327 us; speedup vs baseline: 1.0330x; 1.0330x over previous
//
#include <hip/hip_runtime.h>
#include <math.h>

#define B 4
#define S 2048
#define D 1024
#define H 16
#define DK 64
#define MS (B * S)   // 8192
#define GKA 2048     // split storage width: [hi | lo]

typedef short bf16x8 __attribute__((ext_vector_type(8)));
typedef float f32x4 __attribute__((ext_vector_type(4)));

__device__ __forceinline__ unsigned short f2bf(float x) {
  union { float f; unsigned u; } v; v.f = x;
  unsigned r = v.u + 0x7fff + ((v.u >> 16) & 1);  // RNE
  return (unsigned short)(r >> 16);
}
__device__ __forceinline__ float bf2f(unsigned short h) {
  union { unsigned u; float f; } v; v.u = ((unsigned)h) << 16;
  return v.f;
}
__device__ __forceinline__ void split2(float x, unsigned short& hi, unsigned short& lo) {
  hi = f2bf(x);
  lo = f2bf(x - bf2f(hi));
}

// ---------------------------------------------------------------------------
// prep: ALL input preprocessing in one launch, chunked by blockIdx.x:
//  [0,24576)      split k,v,q -> KSP,VSP,QSP  [8192][2048] ([hi|lo])
//  [24576,32768)  split wk,wv -> WKS,WVS      [1024][2048] (B^T layout)
//  [32768,36864)  split wq    -> WQA [16][1024][128] (A layout, [hi|lo] along k)
//  [36864,37888)  cast wo     -> WOB [1024][1024] plain bf16 (B^T layout)
//  [37888,38144)  zero M
// ---------------------------------------------------------------------------
__global__ __launch_bounds__(256) void prep_kernel(
    const float* __restrict__ q, const float* __restrict__ k, const float* __restrict__ v,
    const float* __restrict__ wk, const float* __restrict__ wv, const float* __restrict__ wq,
    const float* __restrict__ wo,
    unsigned short* __restrict__ KSP, unsigned short* __restrict__ VSP,
    unsigned short* __restrict__ QSP,
    unsigned short* __restrict__ WKS, unsigned short* __restrict__ WVS,
    unsigned short* __restrict__ WQA, unsigned short* __restrict__ WOB,
    float* __restrict__ M) {
  const int blk = blockIdx.x;
  const int tid = threadIdx.x;
  if (blk < 24576) {  // activation splits
    const int which = blk >> 13;
    const int bb = blk & 8191;
    const float* X = which == 0 ? k : (which == 1 ? v : q);
    unsigned short* O = which == 0 ? KSP : (which == 1 ? VSP : QSP);
    int t = bb * 256 + tid;
    int idx = t * 4;
    int m = idx >> 10, d = idx & 1023;
    float4 x = *(const float4*)&X[idx];
    union { unsigned short h[4]; ushort4 u; } uh, ul;
    split2(x.x, uh.h[0], ul.h[0]);
    split2(x.y, uh.h[1], ul.h[1]);
    split2(x.z, uh.h[2], ul.h[2]);
    split2(x.w, uh.h[3], ul.h[3]);
    *(ushort4*)&O[(size_t)m * GKA + d] = uh.u;
    *(ushort4*)&O[(size_t)m * GKA + 1024 + d] = ul.u;
  } else if (blk < 32768) {  // wk/wv splits (B^T layout)
    const int which = (blk - 24576) >> 12;
    const int bb = (blk - 24576) & 4095;
    const float* W = which == 0 ? wk : wv;
    unsigned short* O = which == 0 ? WKS : WVS;
    int t = bb * 256 + tid;
    int d = t & 1023, n = t >> 10;
    int h = n >> 6, dk = n & 63;
    float x = W[((size_t)(h << 10) + d) * 64 + dk];
    unsigned short hi, lo;
    split2(x, hi, lo);
    size_t ro = (size_t)n * GKA + d;
    O[ro] = hi;
    O[ro + 1024] = lo;
  } else if (blk < 36864) {  // wq split (A layout: [h][d][hi 64|lo 64])
    int t = (blk - 32768) * 256 + tid;  // 1M = 16*1024*64
    int kk = t & 63;
    int hd = t >> 6;  // h*1024 + d
    float x = wq[t];
    unsigned short hi, lo;
    split2(x, hi, lo);
    WQA[(size_t)hd * 128 + kk] = hi;
    WQA[(size_t)hd * 128 + 64 + kk] = lo;
  } else if (blk < 37888) {  // wo cast
    int t = (blk - 36864) * 256 + tid;
    int idx = t * 4;
    float4 x = *(const float4*)&wo[idx];
    ushort4 u;
    u.x = f2bf(x.x); u.y = f2bf(x.y); u.z = f2bf(x.z); u.w = f2bf(x.w);
    *(ushort4*)&WOB[idx] = u;
  } else {  // zero M (256 blocks * 256 threads * 4 = 262144 floats)
    int t = (blk - 37888) * 256 + tid;
    *(float4*)&M[(size_t)t * 4] = (float4){0.f, 0.f, 0.f, 0.f};
  }
}

// ---------------------------------------------------------------------------
// gemm_kernel: C[8192 x 1024] = A @ BT^T + bias, fp32 out.
// SPLIT=0 plain-bf16 variant kept for the output projection (K=1024).
// ---------------------------------------------------------------------------
#define BK 32
template <int SPLIT>
__global__ __launch_bounds__(256) void gemm_kernel(
    const unsigned short* __restrict__ A0, const unsigned short* __restrict__ A1,
    const unsigned short* __restrict__ B0, const unsigned short* __restrict__ B1,
    const float* __restrict__ bias0, const float* __restrict__ bias1,
    float* __restrict__ C0, float* __restrict__ C1) {
  const int KLOG = SPLIT ? 3072 : 1024;
  const int AST = SPLIT ? 2048 : 1024;
  const int BST = SPLIT ? 2048 : 1024;
  const unsigned short* A = blockIdx.z ? A1 : A0;
  const unsigned short* BT = blockIdx.z ? B1 : B0;
  const float* bias = blockIdx.z ? bias1 : bias0;
  float* C = blockIdx.z ? C1 : C0;

  __shared__ __align__(16) unsigned short As[128 * BK];
  __shared__ __align__(16) unsigned short Bs[128 * BK];
  const int tid = threadIdx.x;
  const int lane = tid & 63;
  const int w = tid >> 6;
  const int wm = (w >> 1) * 64;
  const int wn = (w & 1) * 64;
  const size_t bm = (size_t)blockIdx.y * 128;
  const size_t bn = (size_t)blockIdx.x * 128;

  f32x4 acc[4][4];
#pragma unroll
  for (int i = 0; i < 4; i++)
#pragma unroll
    for (int j = 0; j < 4; j++) acc[i][j] = (f32x4){0.f, 0.f, 0.f, 0.f};

  const int srow = lane >> 2;
  const int skof = (lane & 3) * 8;
  const unsigned short* Ag0 = A + (bm + w * 32 + srow) * AST + skof;
  const unsigned short* Ag1 = Ag0 + (size_t)16 * AST;
  const unsigned short* Bg0 = BT + (bn + w * 32 + srow) * BST + skof;
  const unsigned short* Bg1 = Bg0 + (size_t)16 * BST;
  unsigned short* As0 = As + (w * 2) * 512;
  unsigned short* As1 = As0 + 512;
  unsigned short* Bs0 = Bs + (w * 2) * 512;
  unsigned short* Bs1 = Bs0 + 512;

  const int fm = lane & 15;
  const int fk = (lane >> 4) * 8;

  for (int k0 = 0; k0 < KLOG; k0 += BK) {
    const int aofs = SPLIT ? (k0 < 2048 ? k0 : k0 - 2048) : k0;
    const int bofs = SPLIT ? (k0 < 1024 ? k0 : k0 - 1024) : k0;
    __syncthreads();
    __builtin_amdgcn_global_load_lds((const __attribute__((address_space(1))) void*)(Ag0 + aofs),
                                     (__attribute__((address_space(3))) void*)As0, 16, 0, 0);
    __builtin_amdgcn_global_load_lds((const __attribute__((address_space(1))) void*)(Ag1 + aofs),
                                     (__attribute__((address_space(3))) void*)As1, 16, 0, 0);
    __builtin_amdgcn_global_load_lds((const __attribute__((address_space(1))) void*)(Bg0 + bofs),
                                     (__attribute__((address_space(3))) void*)Bs0, 16, 0, 0);
    __builtin_amdgcn_global_load_lds((const __attribute__((address_space(1))) void*)(Bg1 + bofs),
                                     (__attribute__((address_space(3))) void*)Bs1, 16, 0, 0);
    __syncthreads();
    bf16x8 af[4], bf[4];
#pragma unroll
    for (int i = 0; i < 4; i++) {
      af[i] = *(const bf16x8*)&As[(wm + i * 16 + fm) * BK + fk];
      bf[i] = *(const bf16x8*)&Bs[(wn + i * 16 + fm) * BK + fk];
    }
#pragma unroll
    for (int i = 0; i < 4; i++)
#pragma unroll
      for (int j = 0; j < 4; j++)
        acc[i][j] = __builtin_amdgcn_mfma_f32_16x16x32_bf16(af[i], bf[j], acc[i][j], 0, 0, 0);
  }

  const int r0 = (lane >> 4) * 4;
#pragma unroll
  for (int i = 0; i < 4; i++)
#pragma unroll
    for (int j = 0; j < 4; j++) {
      size_t row = bm + wm + i * 16 + r0;
      size_t col = bn + wn + j * 16 + fm;
      float bb = bias[col];
#pragma unroll
      for (int r = 0; r < 4; r++) C[(row + r) * D + col] = acc[i][j][r] + bb;
    }
}

// ---------------------------------------------------------------------------
// gemm256_kernel: 256x256-tile 8-wave split-Markidis GEMM (K_logical = 3072)
// for the K/V projections. T2 LDS XOR-swizzle + T3/T4 counted-vmcnt pipeline
// + T5 setprio. C[8192 x 1024] = A @ BT^T + bias, fp32 out.
// A [8192][2048] ([hi|lo] rows), BT [1024][2048], wrap offsets per K-tile.
// grid (4, 32, 2), block 512 (8 waves = 2M x 4N), LDS 128 KiB (2 dbuf).
//
// Swizzle (involution on ushort index, bits 3..5): idx ^= (row & 7) << 3.
// global_load_lds writes LINEAR dest (wave base + lane*16); the SOURCE col is
// pre-swizzled per lane so LDS[swz(p)] = tile[p]; reads apply the same XOR.
// Read conflict check: 16B-slot = (quad | kk<<2) ^ (fm&7) -> 8 lanes/slot,
// the b128 hardware minimum (conflict-free).
//
// Pipeline: loads(t+1) issued at END of iteration t-1 (into the buffer freed
// by tile t-1); at top of iteration t wait vmcnt(8) (= loads(t) landed,
// loads(t+1) still in flight) + raw s_barrier. Never vmcnt(0) in steady state.
// ---------------------------------------------------------------------------
__device__ __forceinline__ void stage256(
    const unsigned short* __restrict__ A, const unsigned short* __restrict__ BT,
    const unsigned* aoffs, const unsigned* boffs,
    unsigned short* Asb, unsigned short* Bsb, int aof, int bof, int w) {
#pragma unroll
  for (int g = 0; g < 4; ++g)
    __builtin_amdgcn_global_load_lds(
        (const __attribute__((address_space(1))) void*)(A + aoffs[g] + aof),
        (__attribute__((address_space(3))) void*)(Asb + g * 4096 + w * 512), 16, 0, 0);
#pragma unroll
  for (int g = 0; g < 4; ++g)
    __builtin_amdgcn_global_load_lds(
        (const __attribute__((address_space(1))) void*)(BT + boffs[g] + bof),
        (__attribute__((address_space(3))) void*)(Bsb + g * 4096 + w * 512), 16, 0, 0);
}

__global__ __launch_bounds__(512, 2) void gemm256_kernel(
    const unsigned short* __restrict__ A0, const unsigned short* __restrict__ A1,
    const unsigned short* __restrict__ B0, const unsigned short* __restrict__ B1,
    const float* __restrict__ bias0, const float* __restrict__ bias1,
    float* __restrict__ C0, float* __restrict__ C1) {
  const unsigned short* __restrict__ A = blockIdx.z ? A1 : A0;
  const unsigned short* __restrict__ BT = blockIdx.z ? B1 : B0;
  const float* __restrict__ bias = blockIdx.z ? bias1 : bias0;
  float* __restrict__ C = blockIdx.z ? C1 : C0;

  __shared__ __align__(16) unsigned short As[2][256 * 64];  // 64 KiB
  __shared__ __align__(16) unsigned short Bs[2][256 * 64];  // 64 KiB

  const int tid = threadIdx.x;
  const int lane = tid & 63;
  const int w = tid >> 6;      // wave 0..7
  const int wr = w >> 2;       // 0..1  (M half: 128 rows)
  const int wc = w & 3;        // 0..3  (N quarter: 64 cols)
  const int fm = lane & 15;
  const int quad = lane >> 4;
  const int sx = (fm & 7) << 3;  // read-side swizzle XOR (ushort units)
  const size_t bm = (size_t)blockIdx.y * 256;
  const size_t bn = (size_t)blockIdx.x * 256;

  // staging source offsets (col pre-swizzled so linear LDS dest = swizzled tile)
  const int srow = tid >> 3;                          // 0..63 within 64-row group
  const int scol = ((tid & 7) ^ (srow & 7)) << 3;     // swizzled col (ushorts)
  unsigned aoffs[4], boffs[4];
#pragma unroll
  for (int g = 0; g < 4; ++g) {
    aoffs[g] = (unsigned)((bm + g * 64 + srow) * 2048 + scol);
    boffs[g] = (unsigned)((bn + g * 64 + srow) * 2048 + scol);
  }

  f32x4 acc[8][4];
#pragma unroll
  for (int i = 0; i < 8; ++i)
#pragma unroll
    for (int j = 0; j < 4; ++j) acc[i][j] = (f32x4){0.f, 0.f, 0.f, 0.f};

  // prologue: tiles 0 and 1 in flight (16 loads outstanding per wave)
  stage256(A, BT, aoffs, boffs, As[0], Bs[0], 0, 0, w);
  stage256(A, BT, aoffs, boffs, As[1], Bs[1], 64, 64, w);

  for (int t = 0; t < 48; ++t) {
    const int cur = t & 1;
    if (t < 47)
      asm volatile("s_waitcnt vmcnt(8)" ::: "memory");  // loads(t) landed; loads(t+1) in flight
    else
      asm volatile("s_waitcnt vmcnt(0)" ::: "memory");  // last tile: drain
    __builtin_amdgcn_s_barrier();
    asm volatile("" ::: "memory");  // keep LDS reads below the barrier

    const unsigned short* Ab = As[cur];
    const unsigned short* Bb = Bs[cur];

    // B fragments for the whole K-tile (8 x ds_read_b128, conflict-free)
    bf16x8 bfr[4][2];
#pragma unroll
    for (int j = 0; j < 4; ++j)
#pragma unroll
      for (int kk = 0; kk < 2; ++kk)
        bfr[j][kk] = *(const bf16x8*)&Bb[((wc * 64 + j * 16 + fm) * 64 + kk * 32 + quad * 8) ^ sx];

    // 4 phases: each = 4 A ds_reads + 16 MFMA (one 32-row quadrant x K=64)
#pragma unroll
    for (int qq = 0; qq < 4; ++qq) {
      bf16x8 afr[2][2];
#pragma unroll
      for (int ii = 0; ii < 2; ++ii)
#pragma unroll
        for (int kk = 0; kk < 2; ++kk)
          afr[ii][kk] = *(const bf16x8*)&Ab[((wr * 128 + (qq * 2 + ii) * 16 + fm) * 64 + kk * 32 + quad * 8) ^ sx];
      __builtin_amdgcn_s_setprio(1);
#pragma unroll
      for (int ii = 0; ii < 2; ++ii)
#pragma unroll
        for (int j = 0; j < 4; ++j) {
          acc[qq * 2 + ii][j] =
              __builtin_amdgcn_mfma_f32_16x16x32_bf16(afr[ii][0], bfr[j][0], acc[qq * 2 + ii][j], 0, 0, 0);
          acc[qq * 2 + ii][j] =
              __builtin_amdgcn_mfma_f32_16x16x32_bf16(afr[ii][1], bfr[j][1], acc[qq * 2 + ii][j], 0, 0, 0);
        }
      __builtin_amdgcn_s_setprio(0);
      __builtin_amdgcn_s_barrier();
      asm volatile("" ::: "memory");  // phase fence
    }

    // issue loads for tile t+2 into buf[cur] (freed by the phase-3 barrier)
    if (t + 2 < 48) {
      const int k0 = (t + 2) * 64;
      const int aof = k0 < 2048 ? k0 : k0 - 2048;  // [hi][lo][hi]
      const int bof = k0 < 1024 ? k0 : k0 - 1024;  // [hi][hi][lo]
      stage256(A, BT, aoffs, boffs, As[cur], Bs[cur], aof, bof, w);
    }
  }

  // epilogue: fp32 C + bias
#pragma unroll
  for (int i = 0; i < 8; ++i)
#pragma unroll
    for (int j = 0; j < 4; ++j) {
      size_t row = bm + wr * 128 + i * 16 + quad * 4;
      size_t col = bn + wc * 64 + j * 16 + fm;
      float bb = bias[col];
#pragma unroll
      for (int r = 0; r < 4; ++r) C[(row + r) * D + col] = acc[i][j][r] + bb;
    }
}

// ---------------------------------------------------------------------------
// gemm_q_softmax: fused logit GEMM + softmax epilogue.
// logits = (QSP @ WQM[b]^T + BQM[b]) * 0.125; heads = softmax per head-row.
// A = QSP [8192][2048] split; B = WQM[b] [1024][2048] split (Wq' = Wq*M[b,h]);
// bias BQM [4][1024] (bq*M). Output HB plain bf16 [8192][1024].
// Each wave's 64 cols = exactly one head; rows complete in-wave.
// ---------------------------------------------------------------------------
__global__ __launch_bounds__(256) void gemm_q_softmax(
    const unsigned short* __restrict__ A, const unsigned short* __restrict__ WQM,
    const float* __restrict__ BQM, unsigned short* __restrict__ HB) {
  const int b = blockIdx.y >> 4;
  const unsigned short* BT = WQM + (size_t)b * D * GKA;

  __shared__ __align__(16) unsigned short As[128 * BK];
  __shared__ __align__(16) unsigned short Bs[128 * BK];
  const int tid = threadIdx.x;
  const int lane = tid & 63;
  const int w = tid >> 6;
  const int wm = (w >> 1) * 64;
  const int wn = (w & 1) * 64;
  const size_t bm = (size_t)blockIdx.y * 128;
  const size_t bn = (size_t)blockIdx.x * 128;

  f32x4 acc[4][4];
#pragma unroll
  for (int i = 0; i < 4; i++)
#pragma unroll
    for (int j = 0; j < 4; j++) acc[i][j] = (f32x4){0.f, 0.f, 0.f, 0.f};

  const int srow = lane >> 2;
  const int skof = (lane & 3) * 8;
  const unsigned short* Ag0 = A + (bm + w * 32 + srow) * GKA + skof;
  const unsigned short* Ag1 = Ag0 + (size_t)16 * GKA;
  const unsigned short* Bg0 = BT + (bn + w * 32 + srow) * GKA + skof;
  const unsigned short* Bg1 = Bg0 + (size_t)16 * GKA;
  unsigned short* As0 = As + (w * 2) * 512;
  unsigned short* As1 = As0 + 512;
  unsigned short* Bs0 = Bs + (w * 2) * 512;
  unsigned short* Bs1 = Bs0 + 512;

  const int fm = lane & 15;
  const int fk = (lane >> 4) * 8;

  for (int k0 = 0; k0 < 3072; k0 += BK) {
    const int aofs = (k0 < 2048) ? k0 : k0 - 2048;  // [hi][lo][hi]
    const int bofs = (k0 < 1024) ? k0 : k0 - 1024;  // [hi][hi][lo]
    __syncthreads();
    __builtin_amdgcn_global_load_lds((const __attribute__((address_space(1))) void*)(Ag0 + aofs),
                                     (__attribute__((address_space(3))) void*)As0, 16, 0, 0);
    __builtin_amdgcn_global_load_lds((const __attribute__((address_space(1))) void*)(Ag1 + aofs),
                                     (__attribute__((address_space(3))) void*)As1, 16, 0, 0);
    __builtin_amdgcn_global_load_lds((const __attribute__((address_space(1))) void*)(Bg0 + bofs),
                                     (__attribute__((address_space(3))) void*)Bs0, 16, 0, 0);
    __builtin_amdgcn_global_load_lds((const __attribute__((address_space(1))) void*)(Bg1 + bofs),
                                     (__attribute__((address_space(3))) void*)Bs1, 16, 0, 0);
    __syncthreads();
    bf16x8 af[4], bf[4];
#pragma unroll
    for (int i = 0; i < 4; i++) {
      af[i] = *(const bf16x8*)&As[(wm + i * 16 + fm) * BK + fk];
      bf[i] = *(const bf16x8*)&Bs[(wn + i * 16 + fm) * BK + fk];
    }
#pragma unroll
    for (int i = 0; i < 4; i++)
#pragma unroll
      for (int j = 0; j < 4; j++)
        acc[i][j] = __builtin_amdgcn_mfma_f32_16x16x32_bf16(af[i], bf[j], acc[i][j], 0, 0, 0);
  }

  // epilogue: this wave's 64 cols (head_col0..+63) are one full head
  const int quad = lane >> 4;
  const size_t head_col0 = bn + wn;
  float bj[4];
#pragma unroll
  for (int j = 0; j < 4; j++) bj[j] = BQM[(size_t)b * D + head_col0 + j * 16 + fm];

#pragma unroll
  for (int i = 0; i < 4; i++) {
    f32x4 val[4];
#pragma unroll
    for (int j = 0; j < 4; j++)
#pragma unroll
      for (int r = 0; r < 4; r++) val[j][r] = (acc[i][j][r] + bj[j]) * 0.125f;

    f32x4 mx = val[0];
#pragma unroll
    for (int j = 1; j < 4; j++)
#pragma unroll
      for (int r = 0; r < 4; r++) mx[r] = fmaxf(mx[r], val[j][r]);
#pragma unroll
    for (int off = 1; off < 16; off <<= 1)
#pragma unroll
      for (int r = 0; r < 4; r++) mx[r] = fmaxf(mx[r], __shfl_xor(mx[r], off, 64));

    f32x4 e[4];
    f32x4 sm = (f32x4){0.f, 0.f, 0.f, 0.f};
#pragma unroll
    for (int j = 0; j < 4; j++)
#pragma unroll
      for (int r = 0; r < 4; r++) {
        e[j][r] = __expf(val[j][r] - mx[r]);
        sm[r] += e[j][r];
      }
#pragma unroll
    for (int off = 1; off < 16; off <<= 1)
#pragma unroll
      for (int r = 0; r < 4; r++) sm[r] += __shfl_xor(sm[r], off, 64);

    f32x4 inv;
#pragma unroll
    for (int r = 0; r < 4; r++) inv[r] = 1.0f / sm[r];

#pragma unroll
    for (int j = 0; j < 4; j++)
#pragma unroll
      for (int r = 0; r < 4; r++) {
        size_t row = bm + wm + i * 16 + quad * 4 + r;
        HB[row * D + head_col0 + j * 16 + fm] = f2bf(e[j][r] * inv[r]);
      }
  }
}

// ---------------------------------------------------------------------------
// M[b,h] = kh^T @ vh (64x64 per (b,h)), s-split 8-way with atomics.
// ---------------------------------------------------------------------------
__global__ __launch_bounds__(256) void compute_m_kernel(
    const float* __restrict__ KH, const float* __restrict__ VH, float* __restrict__ Mout) {
  const int sc = blockIdx.x, h = blockIdx.y, b = blockIdx.z;
  const int tid = threadIdx.x;
  const int i0 = (tid >> 4) * 4;
  const int j0 = (tid & 15) * 4;
  __shared__ float ks[16][64], vs[16][64];
  float acc[4][4];
#pragma unroll
  for (int a = 0; a < 4; a++)
#pragma unroll
    for (int c = 0; c < 4; c++) acc[a][c] = 0.f;

  const int s0 = sc * (S / 8);
  const int rr = tid >> 4;
  const int cc = (tid & 15) * 4;
  for (int s = s0; s < s0 + S / 8; s += 16) {
    size_t base = ((size_t)b * S + s + rr) * D + h * 64 + cc;
    __syncthreads();
    *(float4*)&ks[rr][cc] = *(const float4*)&KH[base];
    *(float4*)&vs[rr][cc] = *(const float4*)&VH[base];
    __syncthreads();
#pragma unroll
    for (int ss = 0; ss < 16; ss++) {
      float4 kf = *(const float4*)&ks[ss][i0];
      float4 vf = *(const float4*)&vs[ss][j0];
      float ka[4] = {kf.x, kf.y, kf.z, kf.w};
      float va[4] = {vf.x, vf.y, vf.z, vf.w};
#pragma unroll
      for (int a = 0; a < 4; a++)
#pragma unroll
        for (int c = 0; c < 4; c++) acc[a][c] += ka[a] * va[c];
    }
  }
  float* Mp = Mout + ((size_t)(b * H + h)) * DK * DK;
#pragma unroll
  for (int a = 0; a < 4; a++)
#pragma unroll
    for (int c = 0; c < 4; c++) atomicAdd(&Mp[(i0 + a) * DK + j0 + c], acc[a][c]);
}

// ---------------------------------------------------------------------------
// split_m_bias: M fp32 [bh][64k][64n] -> MSP bf16 [bh][2][64n][64k] (transposed
// hi,lo) AND BQM[bh][64 j] = sum_k bq[h,k]*M[k,j]  (unscaled).
// ---------------------------------------------------------------------------
__global__ __launch_bounds__(256) void split_m_bias_kernel(
    const float* __restrict__ M, const float* __restrict__ bq,
    unsigned short* __restrict__ MSP, float* __restrict__ BQM) {
  const int bh = blockIdx.x;
  const int h = bh & 15;
  const float* Mp = M + (size_t)bh * 4096;
  unsigned short* hiP = MSP + (size_t)bh * 8192;
  unsigned short* loP = hiP + 4096;
  for (int idx = threadIdx.x; idx < 4096; idx += 256) {
    int kk = idx >> 6, nn = idx & 63;
    unsigned short hi, lo;
    split2(Mp[idx], hi, lo);
    hiP[nn * 64 + kk] = hi;
    loP[nn * 64 + kk] = lo;
  }
  if (threadIdx.x < 64) {
    int j = threadIdx.x;
    float a = 0.f;
#pragma unroll 8
    for (int kk = 0; kk < 64; kk++) a += bq[h * 64 + kk] * Mp[kk * 64 + j];
    BQM[(size_t)bh * 64 + j] = a;
  }
}

// ---------------------------------------------------------------------------
// wqm: Wq'[b,h] = Wq[h] @ M[b,h]  (1024x64 per pair), 3-term split MFMA.
// A = WQA [h][1024 d][hi64|lo64]; B = MSP [bh][2][64 n][64 k] (transposed).
// Output WQM [b][n=h*64+j][d hi | 1024+d lo] (B^T layout for gemm_q_softmax).
// grid (16, H, B); block = 64 d-rows; wave w owns d-rows [c*64+w*16, +16).
// ---------------------------------------------------------------------------
__global__ __launch_bounds__(256) void wqm_kernel(
    const unsigned short* __restrict__ WQA, const unsigned short* __restrict__ MSP,
    unsigned short* __restrict__ WQM) {
  const int c = blockIdx.x, h = blockIdx.y, b = blockIdx.z;
  const int tid = threadIdx.x;
  const int lane = tid & 63;
  const int w = tid >> 6;
  const int fm = lane & 15;
  const int quad = lane >> 4;
  const int ko = quad * 8;
  const int dbase = c * 64 + w * 16;

  const unsigned short* arow = WQA + ((size_t)h * 1024 + dbase + fm) * 128;
  bf16x8 ahi0 = *(const bf16x8*)&arow[ko];        // k 0..31 hi
  bf16x8 ahi1 = *(const bf16x8*)&arow[32 + ko];   // k 32..63 hi
  bf16x8 alo0 = *(const bf16x8*)&arow[64 + ko];   // k 0..31 lo
  bf16x8 alo1 = *(const bf16x8*)&arow[96 + ko];   // k 32..63 lo

  const unsigned short* hiP = MSP + ((size_t)(b * H + h)) * 8192;
  const unsigned short* loP = hiP + 4096;
  f32x4 acc[4];
#pragma unroll
  for (int j = 0; j < 4; j++) acc[j] = (f32x4){0.f, 0.f, 0.f, 0.f};
#pragma unroll
  for (int j = 0; j < 4; j++) {
    bf16x8 bhi0 = *(const bf16x8*)&hiP[(j * 16 + fm) * 64 + ko];
    bf16x8 bhi1 = *(const bf16x8*)&hiP[(j * 16 + fm) * 64 + 32 + ko];
    bf16x8 blo0 = *(const bf16x8*)&loP[(j * 16 + fm) * 64 + ko];
    bf16x8 blo1 = *(const bf16x8*)&loP[(j * 16 + fm) * 64 + 32 + ko];
    acc[j] = __builtin_amdgcn_mfma_f32_16x16x32_bf16(ahi0, bhi0, acc[j], 0, 0, 0);
    acc[j] = __builtin_amdgcn_mfma_f32_16x16x32_bf16(ahi1, bhi1, acc[j], 0, 0, 0);
    acc[j] = __builtin_amdgcn_mfma_f32_16x16x32_bf16(alo0, bhi0, acc[j], 0, 0, 0);
    acc[j] = __builtin_amdgcn_mfma_f32_16x16x32_bf16(alo1, bhi1, acc[j], 0, 0, 0);
    acc[j] = __builtin_amdgcn_mfma_f32_16x16x32_bf16(ahi0, blo0, acc[j], 0, 0, 0);
    acc[j] = __builtin_amdgcn_mfma_f32_16x16x32_bf16(ahi1, blo1, acc[j], 0, 0, 0);
  }

  // C[d=dbase+quad*4+r][col j*16+fm]; write split to WQM[b][h*64+col][d]
#pragma unroll
  for (int j = 0; j < 4; j++) {
    int n = h * 64 + j * 16 + fm;
    ushort4 hv, lv;
    unsigned short hi, lo;
    split2(acc[j][0], hi, lo); hv.x = hi; lv.x = lo;
    split2(acc[j][1], hi, lo); hv.y = hi; lv.y = lo;
    split2(acc[j][2], hi, lo); hv.z = hi; lv.z = lo;
    split2(acc[j][3], hi, lo); hv.w = hi; lv.w = lo;
    size_t base = ((size_t)b * D + n) * GKA + dbase + quad * 4;
    *(ushort4*)&WQM[base] = hv;
    *(ushort4*)&WQM[base + 1024] = lv;
  }
}

// ---------------------------------------------------------------------------
extern "C" void kernel_launch(void* const* d_in, const int* in_sizes, int n_in,
                              void* d_out, int out_size, void* d_ws, size_t ws_size,
                              hipStream_t stream) {
  const float* q = (const float*)d_in[0];
  const float* k = (const float*)d_in[1];
  const float* v = (const float*)d_in[2];
  const float* wq_w = (const float*)d_in[3];
  const float* wq_b = (const float*)d_in[4];
  const float* wk_w = (const float*)d_in[5];
  const float* wk_b = (const float*)d_in[6];
  const float* wv_w = (const float*)d_in[7];
  const float* wv_b = (const float*)d_in[8];
  const float* wo_w = (const float*)d_in[9];
  const float* wo_b = (const float*)d_in[10];
  float* out = (float*)d_out;

  // ws (143 MB): KSP 32 (->HB 16 | WQM 16) | VSP 32 (->MSP 1 + BQM) | QSP 32 |
  //              VH 32 | M 1 | WKS 4 | WVS 4 | WQA 4 | WOB 2.   KH lives in d_out.
  unsigned short* KSP = (unsigned short*)d_ws;
  unsigned short* VSP = KSP + (size_t)16 * 1024 * 1024;
  unsigned short* QSP = VSP + (size_t)16 * 1024 * 1024;
  float* VH = (float*)(QSP + (size_t)16 * 1024 * 1024);
  float* M = VH + (size_t)MS * D;
  unsigned short* WKS = (unsigned short*)(M + 256 * 1024);
  unsigned short* WVS = WKS + (size_t)2 * 1024 * 1024;
  unsigned short* WQA = WVS + (size_t)2 * 1024 * 1024;
  unsigned short* WOB = WQA + (size_t)2 * 1024 * 1024;
  // aliases
  float* KH = out;                                   // dead after compute_m
  unsigned short* HB = KSP;                          // KSP dead after gemm KV
  unsigned short* WQM = KSP + (size_t)8 * 1024 * 1024;
  unsigned short* MSP = VSP;                         // VSP dead after gemm KV
  float* BQM = (float*)(VSP + 512 * 1024);

  dim3 blk(256);

  prep_kernel<<<38144, blk, 0, stream>>>(q, k, v, wk_w, wv_w, wq_w, wo_w,
                                         KSP, VSP, QSP, WKS, WVS, WQA, WOB, M);
  gemm256_kernel<<<dim3(4, 32, 2), dim3(512), 0, stream>>>(KSP, VSP, WKS, WVS, wk_b, wv_b, KH, VH);
  compute_m_kernel<<<dim3(8, H, B), blk, 0, stream>>>(KH, VH, M);
  split_m_bias_kernel<<<64, blk, 0, stream>>>(M, wq_b, MSP, BQM);
  wqm_kernel<<<dim3(16, H, B), blk, 0, stream>>>(WQA, MSP, WQM);
  gemm_q_softmax<<<dim3(8, 64), blk, 0, stream>>>(QSP, WQM, BQM, HB);
  gemm_kernel<0><<<dim3(8, 64, 1), blk, 0, stream>>>(HB, HB, WOB, WOB, wo_b, wo_b, out, out);
}